// Round 2
// baseline (1092.055 us; speedup 1.0000x reference)
//
#include <hip/hip_runtime.h>
#include <cstddef>
#include <cstdint>

#define NN 20000
#define NPAD1 20096   // 20000 -> x128
#define MPAD2 40192   // 40000 -> x128
#define SDIM 256

__device__ inline unsigned short f32_to_bf16(float f) {
    uint32_t u = __float_as_uint(f);
    u += 0x7FFFu + ((u >> 16) & 1u);          // round to nearest even
    return (unsigned short)(u >> 16);
}
__device__ inline float bf16_to_f32(unsigned short h) {
    return __uint_as_float((uint32_t)h << 16);
}

// ---------------- nsum: sum over M=2 ----------------
__global__ void nsum_kernel(const float* __restrict__ nodes, float* __restrict__ nsum) {
    int idx = blockIdx.x * 256 + threadIdx.x;      // 20000*512 threads
    int n = idx >> 9;
    int k = idx & 511;
    nsum[idx] = nodes[(size_t)n * 1024 + k] + nodes[(size_t)n * 1024 + 512 + k];
}

// ---------------- c[b,s] = 2 * dot(x[b,s,:], bp) ----------------
__global__ void cvec_kernel(const float* __restrict__ x, const float* __restrict__ bp,
                            float* __restrict__ c) {
    int row = blockIdx.x * 4 + (threadIdx.x >> 6);   // 512 rows
    int lane = threadIdx.x & 63;
    const float* xr = x + (size_t)row * 512;
    float s = 0.f;
    #pragma unroll
    for (int k = 0; k < 512; k += 64) s += xr[k + lane] * bp[k + lane];
    #pragma unroll
    for (int off = 32; off; off >>= 1) s += __shfl_down(s, off);
    if (lane == 0) c[row] = 2.0f * s;
}

// ---------------- degree count ----------------
__global__ void count_kernel(const int* __restrict__ dst, int* __restrict__ cnt, int E) {
    int e = blockIdx.x * 256 + threadIdx.x;
    if (e < E) atomicAdd(&cnt[dst[e]], 1);
}

__global__ void dinv_kernel(const int* __restrict__ cnt, float* __restrict__ dinv, int n) {
    int i = blockIdx.x * 256 + threadIdx.x;
    if (i < n) dinv[i] = rsqrtf((float)(cnt[i] + 1));   // +1 self loop
}

// ---------------- single-block exclusive scan (20000 ints) ----------------
__global__ __launch_bounds__(1024) void scan_kernel(const int* __restrict__ cnt,
                                                    int* __restrict__ offs, int n) {
    __shared__ int wsum[16];
    __shared__ int s_carry;
    int tid = threadIdx.x, lane = tid & 63, wid = tid >> 6;
    if (tid == 0) s_carry = 0;
    __syncthreads();
    for (int base = 0; base < n; base += 1024) {
        int i = base + tid;
        int v = (i < n) ? cnt[i] : 0;
        int x = v;
        #pragma unroll
        for (int off = 1; off < 64; off <<= 1) {
            int t = __shfl_up(x, off);
            if (lane >= off) x += t;
        }
        if (lane == 63) wsum[wid] = x;
        __syncthreads();
        if (wid == 0) {
            int wv = (lane < 16) ? wsum[lane] : 0;
            int wy = wv;
            #pragma unroll
            for (int off = 1; off < 16; off <<= 1) {
                int t = __shfl_up(wy, off);
                if (lane >= off) wy += t;
            }
            if (lane < 16) wsum[lane] = wy - wv;
        }
        __syncthreads();
        int excl = s_carry + wsum[wid] + x - v;
        if (i < n) offs[i] = excl;
        __syncthreads();
        if (tid == 1023) s_carry = excl + v;
        __syncthreads();
    }
    if (threadIdx.x == 0) offs[n] = s_carry;
}

// ---------------- CSR fill ----------------
__global__ void fill_kernel(const int* __restrict__ src, const int* __restrict__ dst,
                            const int* __restrict__ offs, int* __restrict__ cursor,
                            int* __restrict__ csr, int E) {
    int e = blockIdx.x * 256 + threadIdx.x;
    if (e < E) {
        int d = dst[e];
        int pos = atomicAdd(&cursor[d], 1);
        csr[offs[d] + pos] = src[e];
    }
}

// ---------------- yT[b][j][s] = y[b*256+s][j] ----------------
__global__ void transpose_y(const float* __restrict__ y, float* __restrict__ yT) {
    int idx = blockIdx.x * 256 + threadIdx.x;  // 2*512*256
    int s = idx & 255;
    int j = (idx >> 8) & 511;
    int b = idx >> 17;
    yT[idx] = y[((size_t)(b * 256 + s)) * 512 + j];
}

// ---------------- 128x128 fp32 SGEMM, 8x8 micro-tile ----------------
// C = A[M,K]@B[K,N]; M multiple of 128 (padded), N,K multiples of 128/8.
// Output either fp32 (+colbias) or bf16 scaled by dinv[row-node].
__global__ __launch_bounds__(256) void sgemm128(
    const float* __restrict__ A, const float* __restrict__ B,
    int K, int N,
    const float* __restrict__ colbias,
    float* __restrict__ Cf,
    unsigned short* __restrict__ Cb,
    const float* __restrict__ dinv)
{
    __shared__ float As[8][132];
    __shared__ float Bs[8][128];
    const int bm = blockIdx.y * 128, bn = blockIdx.x * 128;
    const int tid = threadIdx.x;
    const int tm = tid >> 4, tn = tid & 15;
    const int arow = tid >> 1, acol = (tid & 1) << 2;
    const int brow = tid >> 5, bcol = (tid & 31) << 2;

    const float* Aptr = A + (size_t)(bm + arow) * K + acol;
    const float* Bptr = B + (size_t)brow * N + bn + bcol;

    float4 av = *(const float4*)Aptr;
    float4 bv = *(const float4*)Bptr;

    float acc[8][8] = {};
    for (int k0 = 0; k0 < K; k0 += 8) {
        __syncthreads();
        As[acol + 0][arow] = av.x; As[acol + 1][arow] = av.y;
        As[acol + 2][arow] = av.z; As[acol + 3][arow] = av.w;
        *(float4*)&Bs[brow][bcol] = bv;
        __syncthreads();
        if (k0 + 8 < K) {
            av = *(const float4*)(Aptr + k0 + 8);
            bv = *(const float4*)(Bptr + (size_t)(k0 + 8) * N);
        }
        #pragma unroll
        for (int kk = 0; kk < 8; ++kk) {
            float a[8], b[8];
            *(float4*)&a[0] = *(const float4*)&As[kk][tm << 2];
            *(float4*)&a[4] = *(const float4*)&As[kk][(tm << 2) + 64];
            *(float4*)&b[0] = *(const float4*)&Bs[kk][tn << 2];
            *(float4*)&b[4] = *(const float4*)&Bs[kk][(tn << 2) + 64];
            #pragma unroll
            for (int i = 0; i < 8; ++i)
                #pragma unroll
                for (int j = 0; j < 8; ++j)
                    acc[i][j] += a[i] * b[j];
        }
    }

    #pragma unroll
    for (int ih = 0; ih < 2; ++ih)
        #pragma unroll
        for (int i = 0; i < 4; ++i) {
            int row = bm + (tm << 2) + i + ih * 64;
            #pragma unroll
            for (int jh = 0; jh < 2; ++jh) {
                int col = bn + (tn << 2) + jh * 64;
                float4 v = make_float4(acc[ih * 4 + i][jh * 4 + 0], acc[ih * 4 + i][jh * 4 + 1],
                                       acc[ih * 4 + i][jh * 4 + 2], acc[ih * 4 + i][jh * 4 + 3]);
                if (Cb) {
                    int node = row < NN ? row : row - NN;
                    if (node >= NN) node = NN - 1;           // pad rows: garbage, stay in-bounds
                    float sc = dinv[node];
                    ushort4 o;
                    o.x = f32_to_bf16(v.x * sc); o.y = f32_to_bf16(v.y * sc);
                    o.z = f32_to_bf16(v.z * sc); o.w = f32_to_bf16(v.w * sc);
                    *(ushort4*)(Cb + (size_t)row * N + col) = o;
                } else {
                    if (colbias) {
                        v.x += colbias[col + 0]; v.y += colbias[col + 1];
                        v.z += colbias[col + 2]; v.w += colbias[col + 3];
                    }
                    *(float4*)(Cf + (size_t)row * N + col) = v;
                }
            }
        }
}

// ---------------- GCN aggregation over bf16 dinv-scaled hw ----------------
__global__ __launch_bounds__(256) void aggregate_b16(
    const unsigned short* __restrict__ hw, const int* __restrict__ offs,
    const int* __restrict__ csr, const float* __restrict__ dinv,
    const float* __restrict__ bias, float* __restrict__ hout)
{
    int n = blockIdx.x, b = blockIdx.y, s = threadIdx.x;
    const unsigned short* hwb = hw + (size_t)b * NN * SDIM;
    float sum = bf16_to_f32(hwb[(size_t)n * SDIM + s]);          // self loop (scaled by dinv[n])
    int e0 = offs[n], e1 = offs[n + 1];
    for (int e = e0; e < e1; ++e) {
        int src = csr[e];
        sum += bf16_to_f32(hwb[(size_t)src * SDIM + s]);
    }
    float v = dinv[n] * sum + bias[s];
    hout[((size_t)b * NN + n) * SDIM + s] = v > 0.f ? v : 0.01f * v;
}

// ---------------- out[b,n] = h[b,n,:]·w_bp + b_bp ----------------
__global__ void out_kernel(const float* __restrict__ h, const float* __restrict__ w_bp,
                           const float* __restrict__ b_bp, float* __restrict__ out) {
    int row = blockIdx.x * 4 + (threadIdx.x >> 6);   // 40000 rows
    int lane = threadIdx.x & 63;
    const float* hr = h + (size_t)row * SDIM;
    float s = 0.f;
    #pragma unroll
    for (int i = 0; i < 4; ++i) s += hr[i * 64 + lane] * w_bp[i * 64 + lane];
    #pragma unroll
    for (int off = 32; off; off >>= 1) s += __shfl_down(s, off);
    if (lane == 0) out[row] = s + b_bp[0];
}

extern "C" void kernel_launch(void* const* d_in, const int* in_sizes, int n_in,
                              void* d_out, int out_size, void* d_ws, size_t ws_size,
                              hipStream_t stream) {
    const float* x     = (const float*)d_in[0];
    const float* nodes = (const float*)d_in[1];
    const int*   eidx  = (const int*)d_in[2];
    const float* Wp    = (const float*)d_in[3];
    const float* bp    = (const float*)d_in[4];
    const float* gcn_W = (const float*)d_in[5];
    const float* gcn_b = (const float*)d_in[6];
    const float* w_bp  = (const float*)d_in[7];
    const float* b_bp  = (const float*)d_in[8];
    const int E = in_sizes[2] / 2;
    const int N = NN;

    char* w = (char*)d_ws;
    auto alloc = [&](size_t bytes) { char* p = w; w += (bytes + 255) & ~(size_t)255; return p; };
    float* nsum  = (float*)alloc((size_t)NPAD1 * 512 * 4);   // 41.2 MB; reused as hw bf16 later
    float* hA    = (float*)alloc((size_t)MPAD2 * 256 * 4);   // 41.2 MB
    float* hB    = (float*)alloc((size_t)MPAD2 * 256 * 4);   // 41.2 MB
    float* y     = (float*)alloc(512 * 512 * 4);
    float* yT    = (float*)alloc((size_t)2 * 512 * 256 * 4);
    float* cvec  = (float*)alloc(512 * 4);
    float* dinv  = (float*)alloc((size_t)N * 4);
    int*   cnt   = (int*)alloc((size_t)N * 4);
    int*   offs  = (int*)alloc((size_t)(N + 1) * 4);
    int*   cursor= (int*)alloc((size_t)N * 4);
    int*   csr   = (int*)alloc((size_t)E * 4);
    unsigned short* hwb16 = (unsigned short*)nsum;           // alias: nsum dead after h0 gemms

    hipMemsetAsync(cnt, 0, (size_t)N * 4, stream);
    hipMemsetAsync(cursor, 0, (size_t)N * 4, stream);

    nsum_kernel<<<40000, 256, 0, stream>>>(nodes, nsum);
    sgemm128<<<dim3(4, 4), 256, 0, stream>>>(x, Wp, 512, 512, nullptr, y, nullptr, nullptr);
    transpose_y<<<1024, 256, 0, stream>>>(y, yT);
    cvec_kernel<<<128, 256, 0, stream>>>(x, bp, cvec);
    count_kernel<<<(E + 255) / 256, 256, 0, stream>>>(eidx + E, cnt, E);
    dinv_kernel<<<(N + 255) / 256, 256, 0, stream>>>(cnt, dinv, N);
    scan_kernel<<<1, 1024, 0, stream>>>(cnt, offs, N);
    fill_kernel<<<(E + 255) / 256, 256, 0, stream>>>(eidx, eidx + E, offs, cursor, csr, E);

    // h0[b,n,s] = nsum[n,:]·yT[b,:,s] + c[b,s]   (fp32 out, padded rows overwritten/ignored)
    for (int b = 0; b < 2; ++b)
        sgemm128<<<dim3(2, NPAD1 / 128), 256, 0, stream>>>(
            nsum, yT + (size_t)b * 512 * 256, 512, 256,
            cvec + b * 256, hA + (size_t)b * NN * 256, nullptr, nullptr);

    float* hin = hA;
    float* hout = hB;
    for (int l = 0; l < 3; ++l) {
        // hw_scaled = dinv[node] * (hin @ W[l])  ->  bf16
        sgemm128<<<dim3(2, MPAD2 / 128), 256, 0, stream>>>(
            hin, gcn_W + (size_t)l * 256 * 256, 256, 256,
            nullptr, nullptr, hwb16, dinv);
        aggregate_b16<<<dim3(N, 2), 256, 0, stream>>>(hwb16, offs, csr, dinv,
                                                      gcn_b + l * 256, hout);
        float* t = hin; hin = hout; hout = t;
    }
    out_kernel<<<10000, 256, 0, stream>>>(hin, w_bp, b_bp, (float*)d_out);
}

// Round 3
// 826.755 us; speedup vs baseline: 1.3209x; 1.3209x over previous
//
#include <hip/hip_runtime.h>
#include <cstddef>
#include <cstdint>

#define NN 20000
#define NPAD1 20096    // nsum row allocation (>= 20032 used by BM=64 tiles)
#define M2 40000       // 2*NN, exactly divisible by 64
#define SDIM 256

__device__ inline unsigned short f32_to_bf16(float f) {
    uint32_t u = __float_as_uint(f);
    u += 0x7FFFu + ((u >> 16) & 1u);
    return (unsigned short)(u >> 16);
}

// ---------------- nsum: sum over M=2 ----------------
__global__ void nsum_kernel(const float* __restrict__ nodes, float* __restrict__ nsum) {
    int idx = blockIdx.x * 256 + threadIdx.x;
    int n = idx >> 9;
    int k = idx & 511;
    nsum[idx] = nodes[(size_t)n * 1024 + k] + nodes[(size_t)n * 1024 + 512 + k];
}

// ---------------- c[b,s] = 2 * dot(x[b,s,:], bp) ----------------
__global__ void cvec_kernel(const float* __restrict__ x, const float* __restrict__ bp,
                            float* __restrict__ c) {
    int row = blockIdx.x * 4 + (threadIdx.x >> 6);
    int lane = threadIdx.x & 63;
    const float* xr = x + (size_t)row * 512;
    float s = 0.f;
    #pragma unroll
    for (int k = 0; k < 512; k += 64) s += xr[k + lane] * bp[k + lane];
    #pragma unroll
    for (int off = 32; off; off >>= 1) s += __shfl_down(s, off);
    if (lane == 0) c[row] = 2.0f * s;
}

// ---------------- degree count ----------------
__global__ void count_kernel(const int* __restrict__ dst, int* __restrict__ cnt, int E) {
    int e = blockIdx.x * 256 + threadIdx.x;
    if (e < E) atomicAdd(&cnt[dst[e]], 1);
}

__global__ void dinv_kernel(const int* __restrict__ cnt, float* __restrict__ dinv, int n) {
    int i = blockIdx.x * 256 + threadIdx.x;
    if (i < n) dinv[i] = rsqrtf((float)(cnt[i] + 1));
}

// ---------------- single-block exclusive scan ----------------
__global__ __launch_bounds__(1024) void scan_kernel(const int* __restrict__ cnt,
                                                    int* __restrict__ offs, int n) {
    __shared__ int wsum[16];
    __shared__ int s_carry;
    int tid = threadIdx.x, lane = tid & 63, wid = tid >> 6;
    if (tid == 0) s_carry = 0;
    __syncthreads();
    for (int base = 0; base < n; base += 1024) {
        int i = base + tid;
        int v = (i < n) ? cnt[i] : 0;
        int x = v;
        #pragma unroll
        for (int off = 1; off < 64; off <<= 1) {
            int t = __shfl_up(x, off);
            if (lane >= off) x += t;
        }
        if (lane == 63) wsum[wid] = x;
        __syncthreads();
        if (wid == 0) {
            int wv = (lane < 16) ? wsum[lane] : 0;
            int wy = wv;
            #pragma unroll
            for (int off = 1; off < 16; off <<= 1) {
                int t = __shfl_up(wy, off);
                if (lane >= off) wy += t;
            }
            if (lane < 16) wsum[lane] = wy - wv;
        }
        __syncthreads();
        int excl = s_carry + wsum[wid] + x - v;
        if (i < n) offs[i] = excl;
        __syncthreads();
        if (tid == 1023) s_carry = excl + v;
        __syncthreads();
    }
    if (threadIdx.x == 0) offs[n] = s_carry;
}

// ---------------- CSR fill ----------------
__global__ void fill_kernel(const int* __restrict__ src, const int* __restrict__ dst,
                            const int* __restrict__ offs, int* __restrict__ cursor,
                            int* __restrict__ csr, int E) {
    int e = blockIdx.x * 256 + threadIdx.x;
    if (e < E) {
        int d = dst[e];
        int pos = atomicAdd(&cursor[d], 1);
        csr[offs[d] + pos] = src[e];
    }
}

// ---------------- yT[b][j][s] = y[b*256+s][j] ----------------
__global__ void transpose_y(const float* __restrict__ y, float* __restrict__ yT) {
    int idx = blockIdx.x * 256 + threadIdx.x;
    int s = idx & 255;
    int j = (idx >> 8) & 511;
    int b = idx >> 17;
    yT[idx] = y[((size_t)(b * 256 + s)) * 512 + j];
}

// ---------------- 64x128-tile fp32 SGEMM, 128 threads, 8x8 micro ----------------
// C = A[M,K]@B[K,N]; M mult of 64 (rows may be padded garbage), N mult of 128, K mult of 8.
__global__ __launch_bounds__(128) void sgemm(
    const float* __restrict__ A, const float* __restrict__ B,
    int K, int N,
    const float* __restrict__ colbias,
    float* __restrict__ Cf,
    unsigned short* __restrict__ Cb,
    const float* __restrict__ dinv)
{
    __shared__ float As[8][68];    // [k][m]
    __shared__ float Bs[8][128];
    const int bm = blockIdx.y * 64, bn = blockIdx.x * 128;
    const int tid = threadIdx.x;
    const int tm = tid >> 4, tn = tid & 15;          // 8 x 16
    const int arow = tid >> 1, acol = (tid & 1) << 2;
    const int brow = tid >> 5, bcol = (tid & 31) << 2;  // rows brow, brow+4

    const float* Aptr = A + (size_t)(bm + arow) * K + acol;
    const float* Bptr = B + (size_t)brow * N + bn + bcol;

    float4 av  = *(const float4*)Aptr;
    float4 bv0 = *(const float4*)Bptr;
    float4 bv1 = *(const float4*)(Bptr + (size_t)4 * N);

    float acc[8][8] = {};
    for (int k0 = 0; k0 < K; k0 += 8) {
        __syncthreads();
        As[acol + 0][arow] = av.x; As[acol + 1][arow] = av.y;
        As[acol + 2][arow] = av.z; As[acol + 3][arow] = av.w;
        *(float4*)&Bs[brow][bcol] = bv0;
        *(float4*)&Bs[brow + 4][bcol] = bv1;
        __syncthreads();
        if (k0 + 8 < K) {
            av  = *(const float4*)(Aptr + k0 + 8);
            bv0 = *(const float4*)(Bptr + (size_t)(k0 + 8) * N);
            bv1 = *(const float4*)(Bptr + (size_t)(k0 + 12) * N);
        }
        #pragma unroll
        for (int kk = 0; kk < 8; ++kk) {
            float a[8], b[8];
            *(float4*)&a[0] = *(const float4*)&As[kk][tm << 2];
            *(float4*)&a[4] = *(const float4*)&As[kk][(tm << 2) + 32];
            *(float4*)&b[0] = *(const float4*)&Bs[kk][tn << 2];
            *(float4*)&b[4] = *(const float4*)&Bs[kk][(tn << 2) + 64];
            #pragma unroll
            for (int i = 0; i < 8; ++i)
                #pragma unroll
                for (int j = 0; j < 8; ++j)
                    acc[i][j] += a[i] * b[j];
        }
    }

    #pragma unroll
    for (int ih = 0; ih < 2; ++ih)
        #pragma unroll
        for (int i = 0; i < 4; ++i) {
            int row = bm + (tm << 2) + i + ih * 32;
            #pragma unroll
            for (int jh = 0; jh < 2; ++jh) {
                int col = bn + (tn << 2) + jh * 64;
                float4 v = make_float4(acc[ih * 4 + i][jh * 4 + 0], acc[ih * 4 + i][jh * 4 + 1],
                                       acc[ih * 4 + i][jh * 4 + 2], acc[ih * 4 + i][jh * 4 + 3]);
                if (Cb) {
                    int node = row < NN ? row : row - NN;
                    if (node >= NN) node = NN - 1;
                    float sc = dinv[node];
                    ushort4 o;
                    o.x = f32_to_bf16(v.x * sc); o.y = f32_to_bf16(v.y * sc);
                    o.z = f32_to_bf16(v.z * sc); o.w = f32_to_bf16(v.w * sc);
                    *(ushort4*)(Cb + (size_t)row * N + col) = o;
                } else {
                    if (colbias) {
                        v.x += colbias[col + 0]; v.y += colbias[col + 1];
                        v.z += colbias[col + 2]; v.w += colbias[col + 3];
                    }
                    *(float4*)(Cf + (size_t)row * N + col) = v;
                }
            }
        }
}

// ---------------- GCN aggregation: one WAVE per (n,b), 8B loads, 4-deep MLP ----------------
__device__ inline float4 dec4(uint2 v) {
    float4 r;
    r.x = __uint_as_float(v.x << 16);
    r.y = __uint_as_float(v.x & 0xffff0000u);
    r.z = __uint_as_float(v.y << 16);
    r.w = __uint_as_float(v.y & 0xffff0000u);
    return r;
}

__global__ __launch_bounds__(256) void aggregate_w(
    const unsigned short* __restrict__ hw, const int* __restrict__ offs,
    const int* __restrict__ csr, const float* __restrict__ dinv,
    const float* __restrict__ bias, float* __restrict__ hout,
    const float* __restrict__ w_bp, const float* __restrict__ b_bp,
    float* __restrict__ out)   // out != null -> fused final projection
{
    int idx = blockIdx.x * 4 + (threadIdx.x >> 6);   // 0..39999
    int lane = threadIdx.x & 63;
    int b = idx >= NN ? 1 : 0;
    int n = idx - b * NN;
    const unsigned short* hwb = hw + (size_t)b * NN * SDIM;
    const unsigned short* self = hwb + (size_t)n * SDIM + (lane << 2);

    float4 acc = dec4(*(const uint2*)self);          // self loop (already * dinv[n])
    int e0 = offs[n], e1 = offs[n + 1];
    int e = e0;
    for (; e + 4 <= e1; e += 4) {
        int s0 = csr[e + 0], s1 = csr[e + 1], s2 = csr[e + 2], s3 = csr[e + 3];
        uint2 v0 = *(const uint2*)(hwb + (size_t)s0 * SDIM + (lane << 2));
        uint2 v1 = *(const uint2*)(hwb + (size_t)s1 * SDIM + (lane << 2));
        uint2 v2 = *(const uint2*)(hwb + (size_t)s2 * SDIM + (lane << 2));
        uint2 v3 = *(const uint2*)(hwb + (size_t)s3 * SDIM + (lane << 2));
        float4 f0 = dec4(v0), f1 = dec4(v1), f2 = dec4(v2), f3 = dec4(v3);
        acc.x += (f0.x + f1.x) + (f2.x + f3.x);
        acc.y += (f0.y + f1.y) + (f2.y + f3.y);
        acc.z += (f0.z + f1.z) + (f2.z + f3.z);
        acc.w += (f0.w + f1.w) + (f2.w + f3.w);
    }
    for (; e < e1; ++e) {
        float4 f = dec4(*(const uint2*)(hwb + (size_t)csr[e] * SDIM + (lane << 2)));
        acc.x += f.x; acc.y += f.y; acc.z += f.z; acc.w += f.w;
    }
    float dn = dinv[n];
    float4 b4 = *(const float4*)(bias + (lane << 2));
    float4 v;
    v.x = fmaf(dn, acc.x, b4.x); v.y = fmaf(dn, acc.y, b4.y);
    v.z = fmaf(dn, acc.z, b4.z); v.w = fmaf(dn, acc.w, b4.w);
    v.x = v.x > 0.f ? v.x : 0.01f * v.x;
    v.y = v.y > 0.f ? v.y : 0.01f * v.y;
    v.z = v.z > 0.f ? v.z : 0.01f * v.z;
    v.w = v.w > 0.f ? v.w : 0.01f * v.w;
    if (out) {
        float4 w4 = *(const float4*)(w_bp + (lane << 2));
        float s = v.x * w4.x + v.y * w4.y + v.z * w4.z + v.w * w4.w;
        #pragma unroll
        for (int off = 32; off; off >>= 1) s += __shfl_down(s, off);
        if (lane == 0) out[idx] = s + b_bp[0];
    } else {
        *(float4*)(hout + (size_t)idx * SDIM + (lane << 2)) = v;
    }
}

extern "C" void kernel_launch(void* const* d_in, const int* in_sizes, int n_in,
                              void* d_out, int out_size, void* d_ws, size_t ws_size,
                              hipStream_t stream) {
    const float* x     = (const float*)d_in[0];
    const float* nodes = (const float*)d_in[1];
    const int*   eidx  = (const int*)d_in[2];
    const float* Wp    = (const float*)d_in[3];
    const float* bp    = (const float*)d_in[4];
    const float* gcn_W = (const float*)d_in[5];
    const float* gcn_b = (const float*)d_in[6];
    const float* w_bp  = (const float*)d_in[7];
    const float* b_bp  = (const float*)d_in[8];
    const int E = in_sizes[2] / 2;
    const int N = NN;

    char* w = (char*)d_ws;
    auto alloc = [&](size_t bytes) { char* p = w; w += (bytes + 255) & ~(size_t)255; return p; };
    float* nsum  = (float*)alloc((size_t)NPAD1 * 512 * 4);   // reused as hwb16 later
    float* hA    = (float*)alloc((size_t)(M2 + 64) * 256 * 4);
    float* hB    = (float*)alloc((size_t)(M2 + 64) * 256 * 4);
    float* y     = (float*)alloc(512 * 512 * 4);
    float* yT    = (float*)alloc((size_t)2 * 512 * 256 * 4);
    float* cvec  = (float*)alloc(512 * 4);
    float* dinv  = (float*)alloc((size_t)N * 4);
    int*   cnt   = (int*)alloc((size_t)N * 4);
    int*   offs  = (int*)alloc((size_t)(N + 1) * 4);
    int*   cursor= (int*)alloc((size_t)N * 4);
    int*   csr   = (int*)alloc((size_t)E * 4);
    unsigned short* hwb16 = (unsigned short*)nsum;

    hipMemsetAsync(cnt, 0, (size_t)N * 4, stream);
    hipMemsetAsync(cursor, 0, (size_t)N * 4, stream);

    nsum_kernel<<<40000, 256, 0, stream>>>(nodes, nsum);
    // y = x @ Wp : M=512 N=512 K=512
    sgemm<<<dim3(4, 8), 128, 0, stream>>>(x, Wp, 512, 512, nullptr, y, nullptr, nullptr);
    transpose_y<<<1024, 256, 0, stream>>>(y, yT);
    cvec_kernel<<<128, 256, 0, stream>>>(x, bp, cvec);
    count_kernel<<<(E + 255) / 256, 256, 0, stream>>>(eidx + E, cnt, E);
    dinv_kernel<<<(N + 255) / 256, 256, 0, stream>>>(cnt, dinv, N);
    scan_kernel<<<1, 1024, 0, stream>>>(cnt, offs, N);
    fill_kernel<<<(E + 255) / 256, 256, 0, stream>>>(eidx, eidx + E, offs, cursor, csr, E);

    // h0[b,n,s] = nsum[n,:]·yT[b,:,s] + c[b,s]  (M=20032 incl. 32 pad rows; b=0 spill
    // lands in b=1's region and is overwritten by the subsequent launch)
    for (int b = 0; b < 2; ++b)
        sgemm<<<dim3(2, 20032 / 64), 128, 0, stream>>>(
            nsum, yT + (size_t)b * 512 * 256, 512, 256,
            cvec + b * 256, hA + (size_t)b * NN * 256, nullptr, nullptr);

    float* hin = hA;
    float* hout = hB;
    for (int l = 0; l < 3; ++l) {
        sgemm<<<dim3(2, M2 / 64), 128, 0, stream>>>(
            hin, gcn_W + (size_t)l * 256 * 256, 256, 256,
            nullptr, nullptr, hwb16, dinv);
        bool last = (l == 2);
        aggregate_w<<<10000, 256, 0, stream>>>(
            hwb16, offs, csr, dinv, gcn_b + l * 256,
            last ? nullptr : hout, w_bp, b_bp,
            last ? (float*)d_out : nullptr);
        float* t = hin; hin = hout; hout = t;
    }
}

// Round 4
// 478.374 us; speedup vs baseline: 2.2828x; 1.7283x over previous
//
#include <hip/hip_runtime.h>
#include <cstddef>
#include <cstdint>

#define NN 20000
#define SDIM 256

typedef short frag16 __attribute__((ext_vector_type(8)));
typedef float f32x4 __attribute__((ext_vector_type(4)));

__device__ inline unsigned short f32_to_bf16(float f) {
    uint32_t u = __float_as_uint(f);
    u += 0x7FFFu + ((u >> 16) & 1u);
    return (unsigned short)(u >> 16);
}

// ---------------- nsum bf16: rows >= NN zeroed (pad to 20096) ----------------
__global__ void nsum_b16(const float* __restrict__ nodes, unsigned short* __restrict__ out) {
    int idx = blockIdx.x * 256 + threadIdx.x;     // quad index, 20096*128 total
    int n = idx >> 7, k4 = (idx & 127) << 2;
    uint2 o;
    if (n < NN) {
        float4 a = *(const float4*)(nodes + (size_t)n * 1024 + k4);
        float4 b = *(const float4*)(nodes + (size_t)n * 1024 + 512 + k4);
        o.x = ((uint32_t)f32_to_bf16(a.y + b.y) << 16) | f32_to_bf16(a.x + b.x);
        o.y = ((uint32_t)f32_to_bf16(a.w + b.w) << 16) | f32_to_bf16(a.z + b.z);
    } else { o.x = 0; o.y = 0; }
    *(uint2*)(out + (size_t)idx * 4) = o;
}

// ---------------- c[b,s] = 2 * dot(x[b,s,:], bp) ----------------
__global__ void cvec_kernel(const float* __restrict__ x, const float* __restrict__ bp,
                            float* __restrict__ c) {
    int row = blockIdx.x * 4 + (threadIdx.x >> 6);
    int lane = threadIdx.x & 63;
    const float* xr = x + (size_t)row * 512;
    float s = 0.f;
    #pragma unroll
    for (int k = 0; k < 512; k += 64) s += xr[k + lane] * bp[k + lane];
    #pragma unroll
    for (int off = 32; off; off >>= 1) s += __shfl_down(s, off);
    if (lane == 0) c[row] = 2.0f * s;
}

__global__ void count_kernel(const int* __restrict__ dst, int* __restrict__ cnt, int E) {
    int e = blockIdx.x * 256 + threadIdx.x;
    if (e < E) atomicAdd(&cnt[dst[e]], 1);
}

__global__ void dinv_kernel(const int* __restrict__ cnt, float* __restrict__ dinv, int n) {
    int i = blockIdx.x * 256 + threadIdx.x;
    if (i < n) dinv[i] = rsqrtf((float)(cnt[i] + 1));
}

// ---------------- single-block exclusive scan, 4 elems/thread ----------------
__global__ __launch_bounds__(1024) void scan_kernel(const int* __restrict__ cnt,
                                                    int* __restrict__ offs, int n) {
    __shared__ int wsum[16];
    __shared__ int s_carry;
    int tid = threadIdx.x, lane = tid & 63, wid = tid >> 6;
    if (tid == 0) s_carry = 0;
    __syncthreads();
    for (int base = 0; base < n; base += 4096) {
        int i4 = base + tid * 4;
        int4 v = make_int4(0, 0, 0, 0);
        if (i4 < n) v = *(const int4*)(cnt + i4);
        int tsum = v.x + v.y + v.z + v.w;
        int x = tsum;
        #pragma unroll
        for (int off = 1; off < 64; off <<= 1) {
            int t = __shfl_up(x, off);
            if (lane >= off) x += t;
        }
        if (lane == 63) wsum[wid] = x;
        __syncthreads();
        if (wid == 0) {
            int wv = (lane < 16) ? wsum[lane] : 0;
            int wy = wv;
            #pragma unroll
            for (int off = 1; off < 16; off <<= 1) {
                int t = __shfl_up(wy, off);
                if (lane >= off) wy += t;
            }
            if (lane < 16) wsum[lane] = wy - wv;
        }
        __syncthreads();
        int excl = s_carry + wsum[wid] + x - tsum;
        if (i4 < n) {
            offs[i4 + 0] = excl;
            offs[i4 + 1] = excl + v.x;
            offs[i4 + 2] = excl + v.x + v.y;
            offs[i4 + 3] = excl + v.x + v.y + v.z;
        }
        __syncthreads();
        if (tid == 1023) s_carry = excl + tsum;
        __syncthreads();
    }
    if (threadIdx.x == 0) offs[n] = s_carry;
}

__global__ void fill_kernel(const int* __restrict__ src, const int* __restrict__ dst,
                            const int* __restrict__ offs, int* __restrict__ cursor,
                            int* __restrict__ csr, int E) {
    int e = blockIdx.x * 256 + threadIdx.x;
    if (e < E) {
        int d = dst[e];
        int pos = atomicAdd(&cursor[d], 1);
        csr[offs[d] + pos] = src[e];
    }
}

// ---------------- fp32 -> bf16 elementwise ----------------
__global__ void tob16(const float* __restrict__ in, unsigned short* __restrict__ out, int n) {
    int i = blockIdx.x * 256 + threadIdx.x;
    if (i < n) out[i] = f32_to_bf16(in[i]);
}

// ---------------- WT[l][o][i] = W[l][i][o] as bf16 ----------------
__global__ void wtrans(const float* __restrict__ W, unsigned short* __restrict__ WT) {
    int idx = blockIdx.x * 256 + threadIdx.x;     // 3*65536
    int l = idx >> 16, rem = idx & 65535, o = rem >> 8, i = rem & 255;
    WT[idx] = f32_to_bf16(W[(l << 16) + (i << 8) + o]);
}

// ---------------- 64x128-tile fp32 SGEMM (y = x @ Wp only) ----------------
__global__ __launch_bounds__(128) void sgemm(
    const float* __restrict__ A, const float* __restrict__ B,
    int K, int N, float* __restrict__ Cf)
{
    __shared__ float As[8][68];
    __shared__ float Bs[8][128];
    const int bm = blockIdx.y * 64, bn = blockIdx.x * 128;
    const int tid = threadIdx.x;
    const int tm = tid >> 4, tn = tid & 15;
    const int arow = tid >> 1, acol = (tid & 1) << 2;
    const int brow = tid >> 5, bcol = (tid & 31) << 2;

    const float* Aptr = A + (size_t)(bm + arow) * K + acol;
    const float* Bptr = B + (size_t)brow * N + bn + bcol;
    float4 av  = *(const float4*)Aptr;
    float4 bv0 = *(const float4*)Bptr;
    float4 bv1 = *(const float4*)(Bptr + (size_t)4 * N);

    float acc[8][8] = {};
    for (int k0 = 0; k0 < K; k0 += 8) {
        __syncthreads();
        As[acol + 0][arow] = av.x; As[acol + 1][arow] = av.y;
        As[acol + 2][arow] = av.z; As[acol + 3][arow] = av.w;
        *(float4*)&Bs[brow][bcol] = bv0;
        *(float4*)&Bs[brow + 4][bcol] = bv1;
        __syncthreads();
        if (k0 + 8 < K) {
            av  = *(const float4*)(Aptr + k0 + 8);
            bv0 = *(const float4*)(Bptr + (size_t)(k0 + 8) * N);
            bv1 = *(const float4*)(Bptr + (size_t)(k0 + 12) * N);
        }
        #pragma unroll
        for (int kk = 0; kk < 8; ++kk) {
            float a[8], b[8];
            *(float4*)&a[0] = *(const float4*)&As[kk][tm << 2];
            *(float4*)&a[4] = *(const float4*)&As[kk][(tm << 2) + 32];
            *(float4*)&b[0] = *(const float4*)&Bs[kk][tn << 2];
            *(float4*)&b[4] = *(const float4*)&Bs[kk][(tn << 2) + 64];
            #pragma unroll
            for (int i = 0; i < 8; ++i)
                #pragma unroll
                for (int j = 0; j < 8; ++j)
                    acc[i][j] += a[i] * b[j];
        }
    }
    #pragma unroll
    for (int ih = 0; ih < 2; ++ih)
        #pragma unroll
        for (int i = 0; i < 4; ++i) {
            int row = bm + (tm << 2) + i + ih * 32;
            #pragma unroll
            for (int jh = 0; jh < 2; ++jh) {
                int col = bn + (tn << 2) + jh * 64;
                float4 v = make_float4(acc[ih * 4 + i][jh * 4 + 0], acc[ih * 4 + i][jh * 4 + 1],
                                       acc[ih * 4 + i][jh * 4 + 2], acc[ih * 4 + i][jh * 4 + 3]);
                *(float4*)(Cf + (size_t)row * N + col) = v;
            }
        }
}

// ---------------- bf16 MFMA GEMM (m97-style gemm_bt) ----------------
// C[M,N](bf16) = A[M,K](bf16) @ BT[N,K](bf16)^T ; optional +colbias[n], x dinv[node(m)]
__global__ __launch_bounds__(256) void mgemm(
    const unsigned short* __restrict__ A, const unsigned short* __restrict__ BT,
    int K, int N,
    const float* __restrict__ colbias, const float* __restrict__ dinv,
    unsigned short* __restrict__ C)
{
    __shared__ __align__(16) unsigned short As[128 * 32];
    __shared__ __align__(16) unsigned short Bs[128 * 32];
    const int bm = blockIdx.y * 128, bn = blockIdx.x * 128;
    const int tid = threadIdx.x;
    const int lane = tid & 63, w = tid >> 6;
    const int wm = (w >> 1) << 6, wn = (w & 1) << 6;
    const int r = lane & 15, q = lane >> 4;

    f32x4 acc[4][4] = {};

    for (int k0 = 0; k0 < K; k0 += 32) {
        __syncthreads();
        #pragma unroll
        for (int t = 0; t < 2; ++t) {
            int c = t * 256 + w * 64 + lane;         // 16B chunk id; 4 chunks per 32-elem row
            int row = c >> 2, col = (c & 3) << 3;
            __builtin_amdgcn_global_load_lds(
                (const __attribute__((address_space(1))) void*)(A + (size_t)(bm + row) * K + k0 + col),
                (__attribute__((address_space(3))) void*)(As + (size_t)(t * 256 + w * 64) * 8),
                16, 0, 0);
            __builtin_amdgcn_global_load_lds(
                (const __attribute__((address_space(1))) void*)(BT + (size_t)(bn + row) * K + k0 + col),
                (__attribute__((address_space(3))) void*)(Bs + (size_t)(t * 256 + w * 64) * 8),
                16, 0, 0);
        }
        __syncthreads();
        frag16 af[4], bf[4];
        #pragma unroll
        for (int i = 0; i < 4; ++i)
            af[i] = *(const frag16*)(As + ((wm + i * 16 + r) << 5) + (q << 3));
        #pragma unroll
        for (int j = 0; j < 4; ++j)
            bf[j] = *(const frag16*)(Bs + ((wn + j * 16 + r) << 5) + (q << 3));
        #pragma unroll
        for (int i = 0; i < 4; ++i)
            #pragma unroll
            for (int j = 0; j < 4; ++j)
                acc[i][j] = __builtin_amdgcn_mfma_f32_16x16x32_bf16(af[i], bf[j], acc[i][j], 0, 0, 0);
    }

    // C/D layout: col = lane&15 (r), row = q*4 + reg
    #pragma unroll
    for (int i = 0; i < 4; ++i) {
        #pragma unroll
        for (int rg = 0; rg < 4; ++rg) {
            int m = bm + wm + i * 16 + (q << 2) + rg;
            float sc = 1.0f;
            if (dinv) {
                int node = m < NN ? m : m - NN;
                if (node >= NN) node = NN - 1;       // pad rows: finite garbage
                sc = dinv[node];
            }
            #pragma unroll
            for (int j = 0; j < 4; ++j) {
                int n = bn + wn + j * 16 + r;
                float v = acc[i][j][rg] * sc;
                if (colbias) v += colbias[n];
                C[(size_t)m * N + n] = f32_to_bf16(v);
            }
        }
    }
}

// ---------------- GCN aggregation: one wave per (n,b), bf16 in/out ----------------
__device__ inline float4 dec4(uint2 v) {
    float4 r;
    r.x = __uint_as_float(v.x << 16);
    r.y = __uint_as_float(v.x & 0xffff0000u);
    r.z = __uint_as_float(v.y << 16);
    r.w = __uint_as_float(v.y & 0xffff0000u);
    return r;
}

__global__ __launch_bounds__(256) void aggregate_w(
    const unsigned short* __restrict__ hw, const int* __restrict__ offs,
    const int* __restrict__ csr, const float* __restrict__ dinv,
    const float* __restrict__ bias, unsigned short* __restrict__ hout,
    const float* __restrict__ w_bp, const float* __restrict__ b_bp,
    float* __restrict__ out)
{
    int idx = blockIdx.x * 4 + (threadIdx.x >> 6);   // 0..39999
    int lane = threadIdx.x & 63;
    int b = idx >= NN ? 1 : 0;
    int n = idx - b * NN;
    const unsigned short* hwb = hw + (size_t)b * NN * SDIM;

    float4 acc = dec4(*(const uint2*)(hwb + (size_t)n * SDIM + (lane << 2)));
    int e0 = offs[n], e1 = offs[n + 1];
    int e = e0;
    for (; e + 4 <= e1; e += 4) {
        int s0 = csr[e + 0], s1 = csr[e + 1], s2 = csr[e + 2], s3 = csr[e + 3];
        float4 f0 = dec4(*(const uint2*)(hwb + (size_t)s0 * SDIM + (lane << 2)));
        float4 f1 = dec4(*(const uint2*)(hwb + (size_t)s1 * SDIM + (lane << 2)));
        float4 f2 = dec4(*(const uint2*)(hwb + (size_t)s2 * SDIM + (lane << 2)));
        float4 f3 = dec4(*(const uint2*)(hwb + (size_t)s3 * SDIM + (lane << 2)));
        acc.x += (f0.x + f1.x) + (f2.x + f3.x);
        acc.y += (f0.y + f1.y) + (f2.y + f3.y);
        acc.z += (f0.z + f1.z) + (f2.z + f3.z);
        acc.w += (f0.w + f1.w) + (f2.w + f3.w);
    }
    for (; e < e1; ++e) {
        float4 f = dec4(*(const uint2*)(hwb + (size_t)csr[e] * SDIM + (lane << 2)));
        acc.x += f.x; acc.y += f.y; acc.z += f.z; acc.w += f.w;
    }
    float dn = dinv[n];
    float4 b4 = *(const float4*)(bias + (lane << 2));
    float4 v;
    v.x = fmaf(dn, acc.x, b4.x); v.y = fmaf(dn, acc.y, b4.y);
    v.z = fmaf(dn, acc.z, b4.z); v.w = fmaf(dn, acc.w, b4.w);
    v.x = v.x > 0.f ? v.x : 0.01f * v.x;
    v.y = v.y > 0.f ? v.y : 0.01f * v.y;
    v.z = v.z > 0.f ? v.z : 0.01f * v.z;
    v.w = v.w > 0.f ? v.w : 0.01f * v.w;
    if (out) {
        float4 w4 = *(const float4*)(w_bp + (lane << 2));
        float s = v.x * w4.x + v.y * w4.y + v.z * w4.z + v.w * w4.w;
        #pragma unroll
        for (int off = 32; off; off >>= 1) s += __shfl_down(s, off);
        if (lane == 0) out[idx] = s + b_bp[0];
    } else {
        uint2 o;
        o.x = ((uint32_t)f32_to_bf16(v.y) << 16) | f32_to_bf16(v.x);
        o.y = ((uint32_t)f32_to_bf16(v.w) << 16) | f32_to_bf16(v.z);
        *(uint2*)(hout + (size_t)idx * SDIM + (lane << 2)) = o;
    }
}

extern "C" void kernel_launch(void* const* d_in, const int* in_sizes, int n_in,
                              void* d_out, int out_size, void* d_ws, size_t ws_size,
                              hipStream_t stream) {
    const float* x     = (const float*)d_in[0];
    const float* nodes = (const float*)d_in[1];
    const int*   eidx  = (const int*)d_in[2];
    const float* Wp    = (const float*)d_in[3];
    const float* bp    = (const float*)d_in[4];
    const float* gcn_W = (const float*)d_in[5];
    const float* gcn_b = (const float*)d_in[6];
    const float* w_bp  = (const float*)d_in[7];
    const float* b_bp  = (const float*)d_in[8];
    const int E = in_sizes[2] / 2;
    const int N = NN;

    char* w = (char*)d_ws;
    auto alloc = [&](size_t bytes) { char* p = w; w += (bytes + 255) & ~(size_t)255; return p; };
    unsigned short* nsum16 = (unsigned short*)alloc((size_t)20096 * 512 * 2); // reused as hw16
    unsigned short* hA     = (unsigned short*)alloc((size_t)40192 * 256 * 2);
    unsigned short* hB     = (unsigned short*)alloc((size_t)40192 * 256 * 2);
    float* y    = (float*)alloc(512 * 512 * 4);
    unsigned short* yb = (unsigned short*)alloc(512 * 512 * 2);
    unsigned short* WT = (unsigned short*)alloc((size_t)3 * 256 * 256 * 2);
    float* cvec = (float*)alloc(512 * 4);
    float* dinv = (float*)alloc((size_t)N * 4);
    int*   cnt    = (int*)alloc((size_t)N * 4);
    int*   offs   = (int*)alloc((size_t)(N + 1) * 4);
    int*   cursor = (int*)alloc((size_t)N * 4);
    int*   csr    = (int*)alloc((size_t)E * 4);
    unsigned short* hw16 = nsum16;   // alias: nsum dead after h0 GEMMs

    hipMemsetAsync(cnt, 0, (size_t)N * 4, stream);
    hipMemsetAsync(cursor, 0, (size_t)N * 4, stream);

    nsum_b16<<<10048, 256, 0, stream>>>(nodes, nsum16);
    sgemm<<<dim3(4, 8), 128, 0, stream>>>(x, Wp, 512, 512, y);
    tob16<<<1024, 256, 0, stream>>>(y, yb, 512 * 512);
    wtrans<<<768, 256, 0, stream>>>(gcn_W, WT);
    cvec_kernel<<<128, 256, 0, stream>>>(x, bp, cvec);
    count_kernel<<<(E + 255) / 256, 256, 0, stream>>>(eidx + E, cnt, E);
    dinv_kernel<<<(N + 255) / 256, 256, 0, stream>>>(cnt, dinv, N);
    scan_kernel<<<1, 1024, 0, stream>>>(cnt, offs, N);
    fill_kernel<<<(E + 255) / 256, 256, 0, stream>>>(eidx, eidx + E, offs, cursor, csr, E);

    // h0[b*NN+n][s] = nsum[n,:]·y[b*256+s,:] + c[b,s]; b=0 pad spill overwritten by b=1
    for (int b = 0; b < 2; ++b)
        mgemm<<<dim3(2, 157), 256, 0, stream>>>(
            nsum16, yb + (size_t)b * 256 * 512, 512, 256,
            cvec + b * 256, nullptr, hA + (size_t)b * NN * 256);

    unsigned short* hin = hA;
    unsigned short* hout = hB;
    for (int l = 0; l < 3; ++l) {
        mgemm<<<dim3(2, 313), 256, 0, stream>>>(
            hin, WT + (size_t)l * 256 * 256, 256, 256,
            nullptr, dinv, hw16);
        bool last = (l == 2);
        aggregate_w<<<10000, 256, 0, stream>>>(
            hw16, offs, csr, dinv, gcn_b + l * 256,
            last ? nullptr : hout, w_bp, b_bp,
            last ? (float*)d_out : nullptr);
        unsigned short* t = hin; hin = hout; hout = t;
    }
}

// Round 5
// 422.177 us; speedup vs baseline: 2.5867x; 1.1331x over previous
//
#include <hip/hip_runtime.h>
#include <cstddef>
#include <cstdint>

#define NN 20000
#define SDIM 256

typedef short frag16 __attribute__((ext_vector_type(8)));
typedef float f32x4 __attribute__((ext_vector_type(4)));

__device__ inline unsigned short f32_to_bf16(float f) {
    uint32_t u = __float_as_uint(f);
    u += 0x7FFFu + ((u >> 16) & 1u);
    return (unsigned short)(u >> 16);
}

// ---------------- nsum bf16: rows >= NN zeroed (pad to 20096) ----------------
__global__ void nsum_b16(const float* __restrict__ nodes, unsigned short* __restrict__ out) {
    int idx = blockIdx.x * 256 + threadIdx.x;     // quad index, 20096*128 total
    int n = idx >> 7, k4 = (idx & 127) << 2;
    uint2 o;
    if (n < NN) {
        float4 a = *(const float4*)(nodes + (size_t)n * 1024 + k4);
        float4 b = *(const float4*)(nodes + (size_t)n * 1024 + 512 + k4);
        o.x = ((uint32_t)f32_to_bf16(a.y + b.y) << 16) | f32_to_bf16(a.x + b.x);
        o.y = ((uint32_t)f32_to_bf16(a.w + b.w) << 16) | f32_to_bf16(a.z + b.z);
    } else { o.x = 0; o.y = 0; }
    *(uint2*)(out + (size_t)idx * 4) = o;
}

// ---------------- fp32 -> bf16, 4 elems/thread ----------------
__global__ void tob16v(const float* __restrict__ in, unsigned short* __restrict__ out) {
    int i = blockIdx.x * 256 + threadIdx.x;
    float4 v = *(const float4*)(in + (size_t)i * 4);
    uint2 o;
    o.x = ((uint32_t)f32_to_bf16(v.y) << 16) | f32_to_bf16(v.x);
    o.y = ((uint32_t)f32_to_bf16(v.w) << 16) | f32_to_bf16(v.z);
    *(uint2*)(out + (size_t)i * 4) = o;
}

// ---------------- tiled transpose f32 -> bf16: out[l][c][r] = in[l][r][c] ----------------
// R, C multiples of 64; grid (C/64, R/64, L)
__global__ __launch_bounds__(256) void transp_b16(const float* __restrict__ in,
                                                  unsigned short* __restrict__ out,
                                                  int R, int C) {
    __shared__ unsigned short t[64][68];
    const float* inp = in + (size_t)blockIdx.z * R * C;
    unsigned short* outp = out + (size_t)blockIdx.z * R * C;
    int r0 = blockIdx.y * 64, c0 = blockIdx.x * 64;
    int tx = threadIdx.x & 15, ty = threadIdx.x >> 4;
    #pragma unroll
    for (int rr = 0; rr < 4; ++rr) {
        int r = ty * 4 + rr;
        float4 v = *(const float4*)(inp + (size_t)(r0 + r) * C + c0 + tx * 4);
        t[tx * 4 + 0][r] = f32_to_bf16(v.x);
        t[tx * 4 + 1][r] = f32_to_bf16(v.y);
        t[tx * 4 + 2][r] = f32_to_bf16(v.z);
        t[tx * 4 + 3][r] = f32_to_bf16(v.w);
    }
    __syncthreads();
    #pragma unroll
    for (int cc = 0; cc < 4; ++cc) {
        int c = ty * 4 + cc;
        ushort4 o = *(ushort4*)&t[c][tx * 4];
        *(ushort4*)(outp + (size_t)(c0 + c) * R + r0 + tx * 4) = o;
    }
}

// ---------------- c[b,s] = 2 * dot(x[b,s,:], bp) ----------------
__global__ void cvec_kernel(const float* __restrict__ x, const float* __restrict__ bp,
                            float* __restrict__ c) {
    int row = blockIdx.x * 4 + (threadIdx.x >> 6);
    int lane = threadIdx.x & 63;
    const float* xr = x + (size_t)row * 512;
    float s = 0.f;
    #pragma unroll
    for (int k = 0; k < 512; k += 64) s += xr[k + lane] * bp[k + lane];
    #pragma unroll
    for (int off = 32; off; off >>= 1) s += __shfl_down(s, off);
    if (lane == 0) c[row] = 2.0f * s;
}

__global__ void count_kernel(const int* __restrict__ dst, int* __restrict__ cnt, int E) {
    int e = blockIdx.x * 256 + threadIdx.x;
    if (e < E) atomicAdd(&cnt[dst[e]], 1);
}

__global__ void dinv_kernel(const int* __restrict__ cnt, float* __restrict__ dinv, int n) {
    int i = blockIdx.x * 256 + threadIdx.x;
    if (i < n) dinv[i] = rsqrtf((float)(cnt[i] + 1));
}

// ---------------- single-block exclusive scan, 4 elems/thread ----------------
__global__ __launch_bounds__(1024) void scan_kernel(const int* __restrict__ cnt,
                                                    int* __restrict__ offs, int n) {
    __shared__ int wsum[16];
    __shared__ int s_carry;
    int tid = threadIdx.x, lane = tid & 63, wid = tid >> 6;
    if (tid == 0) s_carry = 0;
    __syncthreads();
    for (int base = 0; base < n; base += 4096) {
        int i4 = base + tid * 4;
        int4 v = make_int4(0, 0, 0, 0);
        if (i4 < n) v = *(const int4*)(cnt + i4);
        int tsum = v.x + v.y + v.z + v.w;
        int x = tsum;
        #pragma unroll
        for (int off = 1; off < 64; off <<= 1) {
            int t = __shfl_up(x, off);
            if (lane >= off) x += t;
        }
        if (lane == 63) wsum[wid] = x;
        __syncthreads();
        if (wid == 0) {
            int wv = (lane < 16) ? wsum[lane] : 0;
            int wy = wv;
            #pragma unroll
            for (int off = 1; off < 16; off <<= 1) {
                int t = __shfl_up(wy, off);
                if (lane >= off) wy += t;
            }
            if (lane < 16) wsum[lane] = wy - wv;
        }
        __syncthreads();
        int excl = s_carry + wsum[wid] + x - tsum;
        if (i4 < n) {
            offs[i4 + 0] = excl;
            offs[i4 + 1] = excl + v.x;
            offs[i4 + 2] = excl + v.x + v.y;
            offs[i4 + 3] = excl + v.x + v.y + v.z;
        }
        __syncthreads();
        if (tid == 1023) s_carry = excl + tsum;
        __syncthreads();
    }
    if (threadIdx.x == 0) offs[n] = s_carry;
}

__global__ void fill_kernel(const int* __restrict__ src, const int* __restrict__ dst,
                            const int* __restrict__ offs, int* __restrict__ cursor,
                            int* __restrict__ csr, int E) {
    int e = blockIdx.x * 256 + threadIdx.x;
    if (e < E) {
        int d = dst[e];
        int pos = atomicAdd(&cursor[d], 1);
        csr[offs[d] + pos] = src[e];
    }
}

// ---------------- bf16 MFMA GEMM (m97-style gemm_bt) ----------------
// C[M,N] = A[M,K] @ BT[N,K]^T, bf16 in / bf16 out, fp32 accum.
// mode 0: C[m*N+n] = acc
// mode 1: h0-fused: b=n>>8, s=n&255; C[(b*NN+m)*256+s] = acc + colbias[n]; store iff m<NN||b
// mode 2: C[m*N+n] = acc * dinv[node(m)]
__global__ __launch_bounds__(256) void mgemm(
    const unsigned short* __restrict__ A, const unsigned short* __restrict__ BT,
    int K, int N, int mode,
    const float* __restrict__ colbias, const float* __restrict__ dinv,
    unsigned short* __restrict__ C)
{
    __shared__ __align__(16) unsigned short As[128 * 32];
    __shared__ __align__(16) unsigned short Bs[128 * 32];
    const int bm = blockIdx.y * 128, bn = blockIdx.x * 128;
    const int tid = threadIdx.x;
    const int lane = tid & 63, w = tid >> 6;
    const int wm = (w >> 1) << 6, wn = (w & 1) << 6;
    const int r = lane & 15, q = lane >> 4;

    f32x4 acc[4][4] = {};

    for (int k0 = 0; k0 < K; k0 += 32) {
        __syncthreads();
        #pragma unroll
        for (int t = 0; t < 2; ++t) {
            int c = t * 256 + w * 64 + lane;
            int row = c >> 2, col = (c & 3) << 3;
            __builtin_amdgcn_global_load_lds(
                (const __attribute__((address_space(1))) void*)(A + (size_t)(bm + row) * K + k0 + col),
                (__attribute__((address_space(3))) void*)(As + (size_t)(t * 256 + w * 64) * 8),
                16, 0, 0);
            __builtin_amdgcn_global_load_lds(
                (const __attribute__((address_space(1))) void*)(BT + (size_t)(bn + row) * K + k0 + col),
                (__attribute__((address_space(3))) void*)(Bs + (size_t)(t * 256 + w * 64) * 8),
                16, 0, 0);
        }
        __syncthreads();
        frag16 af[4], bf[4];
        #pragma unroll
        for (int i = 0; i < 4; ++i)
            af[i] = *(const frag16*)(As + ((wm + i * 16 + r) << 5) + (q << 3));
        #pragma unroll
        for (int j = 0; j < 4; ++j)
            bf[j] = *(const frag16*)(Bs + ((wn + j * 16 + r) << 5) + (q << 3));
        #pragma unroll
        for (int i = 0; i < 4; ++i)
            #pragma unroll
            for (int j = 0; j < 4; ++j)
                acc[i][j] = __builtin_amdgcn_mfma_f32_16x16x32_bf16(af[i], bf[j], acc[i][j], 0, 0, 0);
    }

    // C/D layout: col = lane&15 (r), row = q*4 + reg
    #pragma unroll
    for (int i = 0; i < 4; ++i) {
        #pragma unroll
        for (int rg = 0; rg < 4; ++rg) {
            int m = bm + wm + i * 16 + (q << 2) + rg;
            float sc = 1.0f;
            if (mode == 2) {
                int node = m < NN ? m : m - NN;
                if (node >= NN) node = NN - 1;
                sc = dinv[node];
            }
            #pragma unroll
            for (int j = 0; j < 4; ++j) {
                int n = bn + wn + j * 16 + r;
                float v = acc[i][j][rg] * sc;
                if (mode == 1) {
                    int b = n >> 8;
                    if (m < NN || b) {
                        v += colbias[n];
                        C[((size_t)(b * NN + m)) * 256 + (n & 255)] = f32_to_bf16(v);
                    }
                } else {
                    C[(size_t)m * N + n] = f32_to_bf16(v);
                }
            }
        }
    }
}

// ---------------- GCN aggregation: one wave per (n,b), bf16 in/out ----------------
__device__ inline float4 dec4(uint2 v) {
    float4 r;
    r.x = __uint_as_float(v.x << 16);
    r.y = __uint_as_float(v.x & 0xffff0000u);
    r.z = __uint_as_float(v.y << 16);
    r.w = __uint_as_float(v.y & 0xffff0000u);
    return r;
}

__global__ __launch_bounds__(256) void aggregate_w(
    const unsigned short* __restrict__ hw, const int* __restrict__ offs,
    const int* __restrict__ csr, const float* __restrict__ dinv,
    const float* __restrict__ bias, unsigned short* __restrict__ hout,
    const float* __restrict__ w_bp, const float* __restrict__ b_bp,
    float* __restrict__ out)
{
    int idx = blockIdx.x * 4 + (threadIdx.x >> 6);
    int lane = threadIdx.x & 63;
    int b = idx >= NN ? 1 : 0;
    int n = idx - b * NN;
    const unsigned short* hwb = hw + (size_t)b * NN * SDIM;

    float4 acc = dec4(*(const uint2*)(hwb + (size_t)n * SDIM + (lane << 2)));
    int e0 = offs[n], e1 = offs[n + 1];
    int e = e0;
    for (; e + 4 <= e1; e += 4) {
        int s0 = csr[e + 0], s1 = csr[e + 1], s2 = csr[e + 2], s3 = csr[e + 3];
        float4 f0 = dec4(*(const uint2*)(hwb + (size_t)s0 * SDIM + (lane << 2)));
        float4 f1 = dec4(*(const uint2*)(hwb + (size_t)s1 * SDIM + (lane << 2)));
        float4 f2 = dec4(*(const uint2*)(hwb + (size_t)s2 * SDIM + (lane << 2)));
        float4 f3 = dec4(*(const uint2*)(hwb + (size_t)s3 * SDIM + (lane << 2)));
        acc.x += (f0.x + f1.x) + (f2.x + f3.x);
        acc.y += (f0.y + f1.y) + (f2.y + f3.y);
        acc.z += (f0.z + f1.z) + (f2.z + f3.z);
        acc.w += (f0.w + f1.w) + (f2.w + f3.w);
    }
    for (; e < e1; ++e) {
        float4 f = dec4(*(const uint2*)(hwb + (size_t)csr[e] * SDIM + (lane << 2)));
        acc.x += f.x; acc.y += f.y; acc.z += f.z; acc.w += f.w;
    }
    float dn = dinv[n];
    float4 b4 = *(const float4*)(bias + (lane << 2));
    float4 v;
    v.x = fmaf(dn, acc.x, b4.x); v.y = fmaf(dn, acc.y, b4.y);
    v.z = fmaf(dn, acc.z, b4.z); v.w = fmaf(dn, acc.w, b4.w);
    v.x = v.x > 0.f ? v.x : 0.01f * v.x;
    v.y = v.y > 0.f ? v.y : 0.01f * v.y;
    v.z = v.z > 0.f ? v.z : 0.01f * v.z;
    v.w = v.w > 0.f ? v.w : 0.01f * v.w;
    if (out) {
        float4 w4 = *(const float4*)(w_bp + (lane << 2));
        float s = v.x * w4.x + v.y * w4.y + v.z * w4.z + v.w * w4.w;
        #pragma unroll
        for (int off = 32; off; off >>= 1) s += __shfl_down(s, off);
        if (lane == 0) out[idx] = s + b_bp[0];
    } else {
        uint2 o;
        o.x = ((uint32_t)f32_to_bf16(v.y) << 16) | f32_to_bf16(v.x);
        o.y = ((uint32_t)f32_to_bf16(v.w) << 16) | f32_to_bf16(v.z);
        *(uint2*)(hout + (size_t)idx * SDIM + (lane << 2)) = o;
    }
}

extern "C" void kernel_launch(void* const* d_in, const int* in_sizes, int n_in,
                              void* d_out, int out_size, void* d_ws, size_t ws_size,
                              hipStream_t stream) {
    const float* x     = (const float*)d_in[0];
    const float* nodes = (const float*)d_in[1];
    const int*   eidx  = (const int*)d_in[2];
    const float* Wp    = (const float*)d_in[3];
    const float* bp    = (const float*)d_in[4];
    const float* gcn_W = (const float*)d_in[5];
    const float* gcn_b = (const float*)d_in[6];
    const float* w_bp  = (const float*)d_in[7];
    const float* b_bp  = (const float*)d_in[8];
    const int E = in_sizes[2] / 2;
    const int N = NN;

    char* w = (char*)d_ws;
    auto alloc = [&](size_t bytes) { char* p = w; w += (bytes + 255) & ~(size_t)255; return p; };
    unsigned short* nsum16 = (unsigned short*)alloc((size_t)20096 * 512 * 2); // reused as hw16
    unsigned short* hA     = (unsigned short*)alloc((size_t)40192 * 256 * 2);
    unsigned short* hB     = (unsigned short*)alloc((size_t)40192 * 256 * 2);
    unsigned short* xb  = (unsigned short*)alloc((size_t)512 * 512 * 2);
    unsigned short* WpT = (unsigned short*)alloc((size_t)512 * 512 * 2);
    unsigned short* yb  = (unsigned short*)alloc((size_t)512 * 512 * 2);
    unsigned short* WT  = (unsigned short*)alloc((size_t)3 * 256 * 256 * 2);
    float* cvec = (float*)alloc(512 * 4);
    float* dinv = (float*)alloc((size_t)N * 4);
    int*   cnt    = (int*)alloc((size_t)N * 4);
    int*   offs   = (int*)alloc((size_t)(N + 1) * 4);
    int*   cursor = (int*)alloc((size_t)N * 4);
    int*   csr    = (int*)alloc((size_t)E * 4);
    unsigned short* hw16 = nsum16;   // alias: nsum dead after h0 GEMM

    hipMemsetAsync(cnt, 0, (size_t)N * 4, stream);
    hipMemsetAsync(cursor, 0, (size_t)N * 4, stream);

    nsum_b16<<<10048, 256, 0, stream>>>(nodes, nsum16);
    tob16v<<<256, 256, 0, stream>>>(x, xb);                       // 512*512 elems
    transp_b16<<<dim3(8, 8, 1), 256, 0, stream>>>(Wp, WpT, 512, 512);
    transp_b16<<<dim3(4, 4, 3), 256, 0, stream>>>(gcn_W, WT, 256, 256);
    cvec_kernel<<<128, 256, 0, stream>>>(x, bp, cvec);
    count_kernel<<<(E + 255) / 256, 256, 0, stream>>>(eidx + E, cnt, E);
    dinv_kernel<<<(N + 255) / 256, 256, 0, stream>>>(cnt, dinv, N);
    scan_kernel<<<1, 1024, 0, stream>>>(cnt, offs, N);
    fill_kernel<<<(E + 255) / 256, 256, 0, stream>>>(eidx, eidx + E, offs, cursor, csr, E);

    // y[bs, j] = sum_k x[bs,k] Wp[k,j]  (bf16 MFMA, C = yb [512,512])
    mgemm<<<dim3(4, 4), 256, 0, stream>>>(xb, WpT, 512, 512, 0, nullptr, nullptr, yb);

    // h0: single fused GEMM over both batches; n>>8 selects b
    mgemm<<<dim3(4, 157), 256, 0, stream>>>(nsum16, yb, 512, 512, 1, cvec, nullptr, hA);

    unsigned short* hin = hA;
    unsigned short* hout = hB;
    for (int l = 0; l < 3; ++l) {
        mgemm<<<dim3(2, 313), 256, 0, stream>>>(
            hin, WT + (size_t)l * 256 * 256, 256, 256, 2, nullptr, dinv, hw16);
        bool last = (l == 2);
        aggregate_w<<<10000, 256, 0, stream>>>(
            hw16, offs, csr, dinv, gcn_b + l * 256,
            last ? nullptr : hout, w_bp, b_bp,
            last ? (float*)d_out : nullptr);
        unsigned short* t = hin; hin = hout; hout = t;
    }
}